// Round 11
// baseline (2899.775 us; speedup 1.0000x reference)
//
#include <hip/hip_runtime.h>
#include <hip/hip_cooperative_groups.h>

// GATv2 2-layer GNN, MI355X. Inputs/out fp32 (proven r3); compute bf16.
// Round-11: SINGLE cooperative mega-kernel. r10 measured ~15µs structural
// cost per dispatch (5 removed -> -84µs); ~10 boundaries remained. All
// phases fused with grid.sync() (+threadfence for cross-XCD visibility):
//  P0 convert+transpose+zero | P1 hist | P2 scan (3 steps) | P3 scatter |
//  P4 gemm1 | P5 agg1 | P6 stats | P7 foldbn | P8 gemm2 | P9 agg2 | P10 pool.
// Phase bodies are the r10-proven kernels, grid-strided.

namespace cg = cooperative_groups;

#define DIN 128
#define F1 256
#define F2 128
#define NEG_SLOPE 0.2f

typedef unsigned short u16;
typedef __attribute__((ext_vector_type(8))) short short8;
typedef __attribute__((ext_vector_type(4))) float floatx4;

__device__ __forceinline__ float bf2f(u16 u) {
  return __uint_as_float(((unsigned int)u) << 16);
}
__device__ __forceinline__ u16 f2bf(float f) {   // round-to-nearest-even
  unsigned int x = __float_as_uint(f);
  return (u16)((x + 0x7fffu + ((x >> 16) & 1u)) >> 16);
}
__device__ __forceinline__ void load8(const u16* p, float (&f)[8]) {
  short8 v = *(const short8*)p;
#pragma unroll
  for (int k = 0; k < 8; k++) f[k] = bf2f((u16)v[k]);
}

struct PTab { const void* src[8]; int off[9]; };

struct MegaParams {
  const void* xsrc; const int* ei; const int* batch;
  const void *Wl1s, *Wr1s, *Wl2s, *Wr2s;
  PTab tab; int ptotal;
  u16 *xb, *pb, *Wl1t, *Wr1t, *Wl2t, *Wr2t;
  int *hist, *rowptr, *cursor, *partials;
  float *gsum, *gsumsq, *rbias;
  int *ssrc;
  u16 *xl1, *xr1, *helu, *xl2, *xr2;
  float *h2;
  void* out;
  int N, E, G, Etot, n4, nchunks, zn;
  float invn;
};

// ---- shared-memory union (16 KB, shared across phases) ----
union SMem {
  int flagvote;
  struct { int tmp[256]; int carry; } scan;
  struct { float S[8][256], Q[8][256]; } stats;   // 16 KB
  struct { float red[8]; } fold;
  struct { float sm[4][128]; } pool;
};

// ---------------- device bodies (r10-proven, parameterized) ----------------
template<int K, bool RB>
__device__ void gemm_body(const u16* __restrict__ A, const u16* __restrict__ Blt,
                          const u16* __restrict__ Brt, int NL,
                          u16* __restrict__ Cl, u16* __restrict__ Cr, int M,
                          const float* __restrict__ rbias, int bx, int by, int tid) {
  const int m0 = bx * 64;
  const int n0g = by * 64;
  const u16* Bt; u16* C; int col0;
  if (n0g < NL) { Bt = Blt; C = Cl; col0 = n0g; }
  else          { Bt = Brt; C = Cr; col0 = n0g - NL; }

  const int wave = tid >> 6, lane = tid & 63;
  const int wm = wave >> 1, wn = wave & 1;
  const int quad = lane >> 4, l16 = lane & 15;

  floatx4 acc[2][2] = {};
#pragma unroll
  for (int k0 = 0; k0 < K; k0 += 32) {
    short8 af[2], bfr[2];
#pragma unroll
    for (int mt = 0; mt < 2; mt++) {
      int row = m0 + wm * 32 + mt * 16 + l16;
      if (row > M - 1) row = M - 1;
      af[mt] = *(const short8*)(A + (size_t)row * K + k0 + quad * 8);
    }
#pragma unroll
    for (int nt = 0; nt < 2; nt++) {
      int nn = col0 + wn * 32 + nt * 16 + l16;
      bfr[nt] = *(const short8*)(Bt + (size_t)nn * K + k0 + quad * 8);
    }
#pragma unroll
    for (int mt = 0; mt < 2; mt++)
#pragma unroll
      for (int nt = 0; nt < 2; nt++)
        acc[mt][nt] = __builtin_amdgcn_mfma_f32_16x16x32_bf16(af[mt], bfr[nt], acc[mt][nt], 0, 0, 0);
  }

#pragma unroll
  for (int mt = 0; mt < 2; mt++)
#pragma unroll
    for (int nt = 0; nt < 2; nt++) {
      float rb = 0.f;
      if (RB) rb = rbias[n0g + wn * 32 + nt * 16 + l16];
#pragma unroll
      for (int r = 0; r < 4; r++) {
        int row = m0 + wm * 32 + mt * 16 + quad * 4 + r;
        if (row < M) {
          int col = col0 + wn * 32 + nt * 16 + l16;
          C[(size_t)row * NL + col] = f2bf(acc[mt][nt][r] + rb);
        }
      }
    }
}

template<int HEADS, int MODE>
__device__ void agg_body(const u16* __restrict__ xl, const u16* __restrict__ xr,
                         const u16* __restrict__ att, const u16* __restrict__ bias,
                         const int* __restrict__ rowptr, const int* __restrict__ ssrc,
                         void* __restrict__ outv, int n, int grp, int tid) {
  constexpr int F = HEADS * 128;
  constexpr int EPI = 4 / HEADS;
  int wave = tid >> 6, lane = tid & 63;
  int node = grp * 4 + wave;
  if (node >= n) return;
  const int q = lane >> 4, l = lane & 15;
  const int eo   = (HEADS == 2) ? (q >> 1) : q;
  const int head = (HEADS == 2) ? (q & 1) : 0;
  const int ch0 = head * 128 + l * 8;

  float xrv[8], attv[8], acc[8];
  load8(xr + (size_t)node * F + ch0, xrv);
  load8(att + ch0, attv);
#pragma unroll
  for (int k = 0; k < 8; k++) acc[k] = 0.f;

  float l_run = 0.f;
  const int jb = rowptr[node], je = rowptr[node + 1];
  for (int j = jb; j < je; j += EPI) {
    int jj = j + eo;
    int src = ssrc[jj < je ? jj : (je - 1)];
    float xlv[8];
    load8(xl + (size_t)src * F + ch0, xlv);
    float s = 0.f;
#pragma unroll
    for (int k = 0; k < 8; k++) {
      float mm = xlv[k] + xrv[k];
      mm = mm > 0.f ? mm : NEG_SLOPE * mm;
      s += mm * attv[k];
    }
#pragma unroll
    for (int m = 1; m <= 8; m <<= 1) s += __shfl_xor(s, m, 64);
    float p = (jj < je) ? __expf(fminf(s, 80.f)) : 0.f;
    l_run += p;
#pragma unroll
    for (int k = 0; k < 8; k++) acc[k] += p * xlv[k];
  }

#pragma unroll
  for (int m = 16 * HEADS; m <= 32; m <<= 1) {
#pragma unroll
    for (int k = 0; k < 8; k++) acc[k] += __shfl_xor(acc[k], m, 64);
    l_run += __shfl_xor(l_run, m, 64);
  }

  if (lane < 16 * HEADS) {
    float inv = 1.f / (l_run + 1e-16f);
    if (MODE == 0) {
      short8 o;
#pragma unroll
      for (int k = 0; k < 8; k++) {
        float t = acc[k] * inv + bf2f(bias[ch0 + k]);
        t = t > 0.f ? t : (__expf(t) - 1.f);        // elu
        o[k] = (short)f2bf(t);
      }
      *(short8*)((u16*)outv + (size_t)node * F + ch0) = o;
    } else {
      float v[8];
#pragma unroll
      for (int k = 0; k < 8; k++) v[k] = acc[k] * inv + bf2f(bias[ch0 + k]);
      float* op = (float*)outv + (size_t)node * F + ch0;
      *(float4*)op = make_float4(v[0], v[1], v[2], v[3]);
      *(float4*)(op + 4) = make_float4(v[4], v[5], v[6], v[7]);
    }
  }
}

__device__ __forceinline__ int lowerb(const int* __restrict__ a, int n, int key) {
  int lo = 0, hi = n;
  while (lo < hi) { int m = (lo + hi) >> 1; if (a[m] < key) lo = m + 1; else hi = m; }
  return lo;
}

// ---------------- the mega-kernel ----------------
__global__ __launch_bounds__(256, 4) void k_mega(MegaParams P) {
  cg::grid_group grid = cg::this_grid();
  __shared__ SMem sm;
  const int tid = threadIdx.x;
  const int NB = gridDim.x;
  const int bId = blockIdx.x;
  const int stride = NB * 256;

  // ---- dtype self-detect (every block; x input is never modified) ----
  if (tid < 64) {
    int cnt = 0;
#pragma unroll
    for (int i = 0; i < 2; ++i) {
      u16 v = ((const u16*)P.xsrc)[2 * (tid + 64 * i)];
      int e = (v >> 7) & 0xFF;
      if (e >= 115 && e <= 130) cnt++;
    }
#pragma unroll
    for (int m = 1; m <= 32; m <<= 1) cnt += __shfl_xor(cnt, m, 64);
    if (tid == 0) sm.flagvote = (cnt < 64) ? 1 : 0;
  }
  __syncthreads();
  const int fl = sm.flagvote;
  __syncthreads();

  // ============ P0: convert x + params + transpose W + zero ============
  for (int i = bId * 256 + tid; i < P.n4; i += stride) {
    if (fl) {
      float4 a = ((const float4*)P.xsrc)[i];
      ushort4 o;
      o.x = f2bf(a.x); o.y = f2bf(a.y); o.z = f2bf(a.z); o.w = f2bf(a.w);
      ((ushort4*)P.xb)[i] = o;
    } else {
      ((ulong1*)P.xb)[i] = ((const ulong1*)P.xsrc)[i];
    }
  }
  if (bId == NB - 1) {
    for (int i = tid; i < P.ptotal; i += 256) {
      int s = 0;
#pragma unroll
      for (int k = 1; k < 8; k++) s += (i >= P.tab.off[k]);
      int local = i - P.tab.off[s];
      P.pb[i] = fl ? f2bf(((const float*)P.tab.src[s])[local])
                   : ((const u16*)P.tab.src[s])[local];
    }
  }
  for (int ii = bId * 256 + tid; ii < 4 * 32768; ii += stride) {
    int seg = ii >> 15, i = ii & 32767;
    const void* s; u16* d; int NL, sh;
    if      (seg == 0) { s = P.Wl1s; d = P.Wl1t; NL = 256; sh = 7; }
    else if (seg == 1) { s = P.Wr1s; d = P.Wr1t; NL = 256; sh = 7; }
    else if (seg == 2) { s = P.Wl2s; d = P.Wl2t; NL = 128; sh = 8; }
    else               { s = P.Wr2s; d = P.Wr2t; NL = 128; sh = 8; }
    int n = i >> sh, k = i & ((1 << sh) - 1);
    d[i] = fl ? f2bf(((const float*)s)[k * NL + n]) : ((const u16*)s)[k * NL + n];
  }
  for (int i = bId * 256 + tid; i < P.zn; i += stride) P.hist[i] = 0;  // hist|gsum|gsumsq
  __threadfence(); grid.sync(); __threadfence();

  // ============ P1: hist ============
  for (int e = bId * 256 + tid; e < P.Etot; e += stride) {
    int dst = (e < P.E) ? P.ei[P.E + e] : (e - P.E);
    atomicAdd(&P.hist[dst], 1);
  }
  __threadfence(); grid.sync(); __threadfence();

  // ============ P2a: per-chunk scans ============
  for (int c = bId; c < P.nchunks; c += NB) {
    int gid = c * 256 + tid;
    int v = (gid < P.N) ? P.hist[gid] : 0;
    sm.scan.tmp[tid] = v;
    __syncthreads();
    for (int off = 1; off < 256; off <<= 1) {
      int add = (tid >= off) ? sm.scan.tmp[tid - off] : 0;
      __syncthreads();
      sm.scan.tmp[tid] += add;
      __syncthreads();
    }
    if (gid < P.N) P.rowptr[gid] = sm.scan.tmp[tid] - v;   // local exclusive
    if (tid == 255) P.partials[c] = sm.scan.tmp[255];
    __syncthreads();
  }
  __threadfence(); grid.sync(); __threadfence();

  // ============ P2b: block 0 scans partials (with carry) ============
  if (bId == 0) {
    if (tid == 0) sm.scan.carry = 0;
    __syncthreads();
    for (int base = 0; base < P.nchunks; base += 256) {
      int idx = base + tid;
      int v = (idx < P.nchunks) ? P.partials[idx] : 0;
      sm.scan.tmp[tid] = v;
      __syncthreads();
      for (int off = 1; off < 256; off <<= 1) {
        int add = (tid >= off) ? sm.scan.tmp[tid - off] : 0;
        __syncthreads();
        sm.scan.tmp[tid] += add;
        __syncthreads();
      }
      int carry = sm.scan.carry;
      if (idx < P.nchunks) P.partials[idx] = sm.scan.tmp[tid] - v + carry;
      __syncthreads();
      if (tid == 255) sm.scan.carry = carry + sm.scan.tmp[255];
      __syncthreads();
    }
  }
  __threadfence(); grid.sync(); __threadfence();

  // ============ P2c: add offsets ============
  for (int gid = bId * 256 + tid; gid < P.N; gid += stride) {
    int v = P.rowptr[gid] + P.partials[gid >> 8];
    P.rowptr[gid] = v;
    P.cursor[gid] = v;
  }
  if (bId == 0 && tid == 0) P.rowptr[P.N] = P.Etot;
  __threadfence(); grid.sync(); __threadfence();

  // ============ P3: scatter ============
  for (int e = bId * 256 + tid; e < P.Etot; e += stride) {
    int src, dst;
    if (e < P.E) { src = P.ei[e]; dst = P.ei[P.E + e]; }
    else         { src = e - P.E; dst = e - P.E; }
    int pos = atomicAdd(&P.cursor[dst], 1);
    P.ssrc[pos] = src;
  }
  __threadfence(); grid.sync(); __threadfence();

  // ============ P4: gemm1 ============
  {
    const int Mt = (P.N + 63) / 64, tiles = Mt * 8;
    for (int t = bId; t < tiles; t += NB)
      gemm_body<DIN, false>(P.xb, P.Wl1t, P.Wr1t, F1, P.xl1, P.xr1, P.N, nullptr,
                            t % Mt, t / Mt, tid);
  }
  __threadfence(); grid.sync(); __threadfence();

  // ============ P5: agg1 ============
  {
    u16* pAtt1 = P.pb + P.tab.off[0];
    u16* pB1   = P.pb + P.tab.off[1];
    const int grps = (P.N + 3) / 4;
    for (int g = bId; g < grps; g += NB)
      agg_body<2, 0>(P.xl1, P.xr1, pAtt1, pB1, P.rowptr, P.ssrc, P.helu, P.N, g, tid);
  }
  __threadfence(); grid.sync(); __threadfence();

  // ============ P6: stats (256 virtual blocks) ============
  for (int vb = bId; vb < 256; vb += NB) {
    int rg = tid >> 5, cl = tid & 31, ch0 = cl * 8;
    float s[8] = {}, q[8] = {};
    for (int r = vb * 8 + rg; r < P.N; r += 256 * 8) {
      float v[8];
      load8(P.helu + (size_t)r * F1 + ch0, v);
#pragma unroll
      for (int k = 0; k < 8; k++) { s[k] += v[k]; q[k] += v[k] * v[k]; }
    }
#pragma unroll
    for (int k = 0; k < 8; k++) { sm.stats.S[rg][ch0 + k] = s[k]; sm.stats.Q[rg][ch0 + k] = q[k]; }
    __syncthreads();
    float ts = 0.f, tq = 0.f;
#pragma unroll
    for (int g = 0; g < 8; g++) { ts += sm.stats.S[g][tid]; tq += sm.stats.Q[g][tid]; }
    atomicAdd(&P.gsum[tid], ts);
    atomicAdd(&P.gsumsq[tid], tq);
    __syncthreads();
  }
  __threadfence(); grid.sync(); __threadfence();

  // ============ P7: foldbn (128 virtual blocks) ============
  {
    u16* pGamma = P.pb + P.tab.off[2];
    u16* pBeta  = P.pb + P.tab.off[3];
    for (int n = bId; n < 128; n += NB) {
      float mu = P.gsum[tid] * P.invn;
      float var = P.gsumsq[tid] * P.invn - mu * mu;
      float a = bf2f(pGamma[tid]) * rsqrtf(fmaxf(var, 0.f) + 1e-5f);
      float b = bf2f(pBeta[tid]) - mu * a;
      float wl = bf2f(P.Wl2t[n * 256 + tid]);
      float wr = bf2f(P.Wr2t[n * 256 + tid]);
      float sl = b * wl, sr = b * wr;
      P.Wl2t[n * 256 + tid] = f2bf(a * wl);
      P.Wr2t[n * 256 + tid] = f2bf(a * wr);
#pragma unroll
      for (int m = 1; m <= 32; m <<= 1) {
        sl += __shfl_xor(sl, m, 64);
        sr += __shfl_xor(sr, m, 64);
      }
      int wave = tid >> 6, lane = tid & 63;
      if (lane == 0) { sm.fold.red[wave] = sl; sm.fold.red[4 + wave] = sr; }
      __syncthreads();
      if (tid == 0) P.rbias[n] = sm.fold.red[0] + sm.fold.red[1] + sm.fold.red[2] + sm.fold.red[3];
      if (tid == 1) P.rbias[128 + n] = sm.fold.red[4] + sm.fold.red[5] + sm.fold.red[6] + sm.fold.red[7];
      __syncthreads();
    }
  }
  __threadfence(); grid.sync(); __threadfence();

  // ============ P8: gemm2 ============
  {
    const int Mt = (P.N + 63) / 64, tiles = Mt * 4;
    for (int t = bId; t < tiles; t += NB)
      gemm_body<F1, true>(P.helu, P.Wl2t, P.Wr2t, F2, P.xl2, P.xr2, P.N, P.rbias,
                          t % Mt, t / Mt, tid);
  }
  __threadfence(); grid.sync(); __threadfence();

  // ============ P9: agg2 ============
  {
    u16* pAtt2 = P.pb + P.tab.off[4];
    u16* pB2   = P.pb + P.tab.off[5];
    const int grps = (P.N + 3) / 4;
    for (int g = bId; g < grps; g += NB)
      agg_body<1, 1>(P.xl2, P.xr2, pAtt2, pB2, P.rowptr, P.ssrc, P.h2, P.N, g, tid);
  }
  __threadfence(); grid.sync(); __threadfence();

  // ============ P10: pool + final linear ============
  {
    u16* pWlin = P.pb + P.tab.off[6];
    u16* pBlin = P.pb + P.tab.off[7];
    int wave = tid >> 6, lane = tid & 63;
    int ch = lane * 2;
    for (int g = bId; g < P.G; g += NB) {
      int jb = lowerb(P.batch, P.N, g);
      int je = lowerb(P.batch, P.N, g + 1);
      float c0 = 0.f, c1 = 0.f;
      for (int r = jb + wave; r < je; r += 4) {
        float2 v = *(const float2*)(P.h2 + (size_t)r * F2 + ch);
        c0 += v.x; c1 += v.y;
      }
      sm.pool.sm[wave][ch] = c0;
      sm.pool.sm[wave][ch + 1] = c1;
      __syncthreads();
      if (wave == 0) {
        c0 = sm.pool.sm[0][ch] + sm.pool.sm[1][ch] + sm.pool.sm[2][ch] + sm.pool.sm[3][ch];
        c1 = sm.pool.sm[0][ch + 1] + sm.pool.sm[1][ch + 1] + sm.pool.sm[2][ch + 1] + sm.pool.sm[3][ch + 1];
        float cf = fmaxf((float)(je - jb), 1.f);
        c0 /= cf; c1 /= cf;
        float s0 = c0 * bf2f(pWlin[ch * 2 + 0]) + c1 * bf2f(pWlin[(ch + 1) * 2 + 0]);
        float s1 = c0 * bf2f(pWlin[ch * 2 + 1]) + c1 * bf2f(pWlin[(ch + 1) * 2 + 1]);
#pragma unroll
        for (int m = 1; m <= 32; m <<= 1) {
          s0 += __shfl_xor(s0, m, 64);
          s1 += __shfl_xor(s1, m, 64);
        }
        if (lane == 0) {
          float o0 = s0 + bf2f(pBlin[0]);
          float o1 = s1 + bf2f(pBlin[1]);
          if (fl) {
            ((float*)P.out)[g * 2 + 0] = o0;
            ((float*)P.out)[g * 2 + 1] = o1;
          } else {
            ((u16*)P.out)[g * 2 + 0] = f2bf(o0);
            ((u16*)P.out)[g * 2 + 1] = f2bf(o1);
          }
        }
      }
      __syncthreads();
    }
  }
}

// ---------------- host ----------------
extern "C" void kernel_launch(void* const* d_in, const int* in_sizes, int n_in,
                              void* d_out, int out_size, void* d_ws, size_t ws_size,
                              hipStream_t stream) {
  const int N = in_sizes[0] / DIN;
  const int E = in_sizes[1] / 2;
  const int G = out_size / 2;
  const int Etot = E + N;

  char* p = (char*)d_ws;
  auto alloc = [&](size_t bytes) {
    char* r = p;
    p += (bytes + 255) & ~(size_t)255;
    return r;
  };
  // zero region (zeroed in P0): hist | gsum | gsumsq  (contiguous, 256-aligned sizes)
  int*   hist    = (int*)alloc((size_t)N * 4);
  float* gsum    = (float*)alloc(1024);
  float* gsumsq  = (float*)alloc(1024);
  int    zn      = (int)(((char*)gsumsq + 1024) - (char*)hist) / 4;
  int*   rowptr  = (int*)alloc((size_t)(N + 1) * 4);
  int*   cursor  = (int*)alloc((size_t)N * 4);
  int*   partials= (int*)alloc(4096);
  float* rbias   = (float*)alloc(256 * 4);
  int*   ssrc    = (int*)alloc((size_t)Etot * 4);
  u16*   xb      = (u16*)alloc((size_t)N * DIN * 2);
  u16*   pb      = (u16*)alloc(4096);
  u16*   Wl1t    = (u16*)alloc(DIN * F1 * 2);
  u16*   Wr1t    = (u16*)alloc(DIN * F1 * 2);
  u16*   Wl2t    = (u16*)alloc(F1 * F2 * 2);
  u16*   Wr2t    = (u16*)alloc(F1 * F2 * 2);
  u16*   regionA = (u16*)alloc((size_t)N * F1 * 2);
  u16*   regionB = (u16*)alloc((size_t)N * F1 * 2);
  u16*   regionC = (u16*)alloc((size_t)N * F1 * 2);

  MegaParams P;
  P.xsrc = d_in[0]; P.ei = (const int*)d_in[1]; P.batch = (const int*)d_in[2];
  P.Wl1s = d_in[3]; P.Wr1s = d_in[4]; P.Wl2s = d_in[9]; P.Wr2s = d_in[10];
  const int pidx[8] = {5, 6, 7, 8, 11, 12, 13, 14};
  int accum = 0;
  for (int i = 0; i < 8; i++) {
    P.tab.src[i] = d_in[pidx[i]];
    P.tab.off[i] = accum;
    accum += in_sizes[pidx[i]];
  }
  P.tab.off[8] = accum;
  P.ptotal = accum;
  P.xb = xb; P.pb = pb; P.Wl1t = Wl1t; P.Wr1t = Wr1t; P.Wl2t = Wl2t; P.Wr2t = Wr2t;
  P.hist = hist; P.rowptr = rowptr; P.cursor = cursor; P.partials = partials;
  P.gsum = gsum; P.gsumsq = gsumsq; P.rbias = rbias; P.ssrc = ssrc;
  P.xl1 = regionA; P.xr1 = regionB; P.helu = regionC;
  P.xl2 = regionB; P.xr2 = regionB + (size_t)N * F2;
  P.h2 = (float*)regionA;
  P.out = d_out;
  P.N = N; P.E = E; P.G = G; P.Etot = Etot;
  P.n4 = in_sizes[0] / 4;
  P.nchunks = (N + 255) / 256;
  P.zn = zn;
  P.invn = 1.0f / (float)N;

  int dev = 0;
  hipGetDevice(&dev);
  int numCU = 256;
  hipDeviceGetAttribute(&numCU, hipDeviceAttributeMultiprocessorCount, dev);
  int maxb = 4;
  hipOccupancyMaxActiveBlocksPerMultiprocessor(&maxb, (const void*)k_mega, 256, 0);
  if (maxb < 1) maxb = 1;
  long grid = (long)maxb * numCU;
  if (grid > 2048) grid = 2048;

  void* args[] = { &P };
  hipLaunchCooperativeKernel((const void*)k_mega, dim3((int)grid), dim3(256),
                             args, 0, stream);
}

// Round 12
// 508.707 us; speedup vs baseline: 5.7003x; 5.7003x over previous
//
#include <hip/hip_runtime.h>

// GATv2 2-layer GNN, MI355X. Inputs/out fp32 (proven r3); compute bf16.
// Round-12: REVERT r11 mega-kernel (grid.sync ~400µs each on MI355X — mass
// polling of one global flag across 8 XCDs; never again). Back to r10 + two
// no-polling fusions: (1) hist lives in gemm1's dispatch (independent work);
// (2) foldbn deleted — stats' last block (atomic done-counter) emits a,b and
// gemm2 applies BN on A-fragments in-register. 11 -> 9 dispatches.

#define DIN 128
#define F1 256
#define F2 128
#define NEG_SLOPE 0.2f

typedef unsigned short u16;
typedef __attribute__((ext_vector_type(8))) short short8;
typedef __attribute__((ext_vector_type(4))) float floatx4;

__device__ __forceinline__ float bf2f(u16 u) {
  return __uint_as_float(((unsigned int)u) << 16);
}
__device__ __forceinline__ u16 f2bf(float f) {   // round-to-nearest-even
  unsigned int x = __float_as_uint(f);
  return (u16)((x + 0x7fffu + ((x >> 16) & 1u)) >> 16);
}
__device__ __forceinline__ void load8(const u16* p, float (&f)[8]) {
  short8 v = *(const short8*)p;
#pragma unroll
  for (int k = 0; k < 8; k++) f[k] = bf2f((u16)v[k]);
}

// ---------------- fused convert + transpose + zero + self-detect (r10) ----------------
struct PTab { const void* src[8]; int off[9]; };
__global__ __launch_bounds__(256) void k_convert_all(
    const void* __restrict__ xsrc, u16* __restrict__ xb, int n4, int nxb,
    PTab t, u16* __restrict__ pb, int ptotal, int npb,
    const void* __restrict__ Wl1s, const void* __restrict__ Wr1s,
    const void* __restrict__ Wl2s, const void* __restrict__ Wr2s,
    u16* __restrict__ Wl1t, u16* __restrict__ Wr1t,
    u16* __restrict__ Wl2t, u16* __restrict__ Wr2t,
    int* __restrict__ zbase, int zn, int* __restrict__ flag) {
  __shared__ int flagS;
  int tid = threadIdx.x;
  if (tid < 64) {
    int cnt = 0;
#pragma unroll
    for (int i = 0; i < 2; ++i) {
      u16 v = ((const u16*)xsrc)[2 * (tid + 64 * i)];
      int e = (v >> 7) & 0xFF;
      if (e >= 115 && e <= 130) cnt++;
    }
#pragma unroll
    for (int m = 1; m <= 32; m <<= 1) cnt += __shfl_xor(cnt, m, 64);
    if (tid == 0) flagS = (cnt < 64) ? 1 : 0;
  }
  __syncthreads();
  const int fl = flagS;
  if (blockIdx.x == 0 && tid == 0) *flag = fl;

  int b = blockIdx.x;
  if (b < nxb) {
    int i = b * 256 + tid;
    if (i >= n4) return;
    if (fl) {
      float4 a = ((const float4*)xsrc)[i];
      ushort4 o;
      o.x = f2bf(a.x); o.y = f2bf(a.y); o.z = f2bf(a.z); o.w = f2bf(a.w);
      ((ushort4*)xb)[i] = o;
    } else {
      ((ulong1*)xb)[i] = ((const ulong1*)xsrc)[i];
    }
    return;
  }
  b -= nxb;
  if (b < npb) {
    int i = b * 256 + tid;
    if (i >= ptotal) return;
    int s = 0;
#pragma unroll
    for (int k = 1; k < 8; k++) s += (i >= t.off[k]);
    int local = i - t.off[s];
    pb[i] = fl ? f2bf(((const float*)t.src[s])[local]) : ((const u16*)t.src[s])[local];
    return;
  }
  b -= npb;
  if (b < 512) {
    int seg = b >> 7;
    int i = (b & 127) * 256 + tid;
    const void* s; u16* d; int NL, sh;
    if      (seg == 0) { s = Wl1s; d = Wl1t; NL = 256; sh = 7; }
    else if (seg == 1) { s = Wr1s; d = Wr1t; NL = 256; sh = 7; }
    else if (seg == 2) { s = Wl2s; d = Wl2t; NL = 128; sh = 8; }
    else               { s = Wr2s; d = Wr2t; NL = 128; sh = 8; }
    int n = i >> sh, k = i & ((1 << sh) - 1);
    int si = k * NL + n;
    d[i] = fl ? f2bf(((const float*)s)[si]) : ((const u16*)s)[si];
    return;
  }
  b -= 512;
  int i = b * 256 + tid;
  if (i < zn) zbase[i] = 0;
}

// ---------------- GEMM body (r10-proven, device fn) ----------------
template<int K, bool RB>
__device__ __forceinline__ void gemm_body(
    const u16* __restrict__ A, const u16* __restrict__ Blt, const u16* __restrict__ Brt,
    int NL, u16* __restrict__ Cl, u16* __restrict__ Cr, int M,
    const float* __restrict__ rbias, int bx, int by, int tid) {
  const int m0 = bx * 64;
  const int n0g = by * 64;
  const u16* Bt; u16* C; int col0;
  if (n0g < NL) { Bt = Blt; C = Cl; col0 = n0g; }
  else          { Bt = Brt; C = Cr; col0 = n0g - NL; }

  const int wave = tid >> 6, lane = tid & 63;
  const int wm = wave >> 1, wn = wave & 1;
  const int quad = lane >> 4, l16 = lane & 15;

  floatx4 acc[2][2] = {};
#pragma unroll
  for (int k0 = 0; k0 < K; k0 += 32) {
    short8 af[2], bfr[2];
#pragma unroll
    for (int mt = 0; mt < 2; mt++) {
      int row = m0 + wm * 32 + mt * 16 + l16;
      if (row > M - 1) row = M - 1;
      af[mt] = *(const short8*)(A + (size_t)row * K + k0 + quad * 8);
    }
#pragma unroll
    for (int nt = 0; nt < 2; nt++) {
      int nn = col0 + wn * 32 + nt * 16 + l16;
      bfr[nt] = *(const short8*)(Bt + (size_t)nn * K + k0 + quad * 8);
    }
#pragma unroll
    for (int mt = 0; mt < 2; mt++)
#pragma unroll
      for (int nt = 0; nt < 2; nt++)
        acc[mt][nt] = __builtin_amdgcn_mfma_f32_16x16x32_bf16(af[mt], bfr[nt], acc[mt][nt], 0, 0, 0);
  }

#pragma unroll
  for (int mt = 0; mt < 2; mt++)
#pragma unroll
    for (int nt = 0; nt < 2; nt++) {
      float rb = 0.f;
      if (RB) rb = rbias[n0g + wn * 32 + nt * 16 + l16];
#pragma unroll
      for (int r = 0; r < 4; r++) {
        int row = m0 + wm * 32 + mt * 16 + quad * 4 + r;
        if (row < M) {
          int col = col0 + wn * 32 + nt * 16 + l16;
          C[(size_t)row * NL + col] = f2bf(acc[mt][nt][r] + rb);
        }
      }
    }
}

// ---------------- D2: hist (+gcnt) fused with gemm1 ----------------
__global__ __launch_bounds__(256) void k_histgemm1(
    const int* __restrict__ ei, int* __restrict__ hist,
    const int* __restrict__ batch, int* __restrict__ gcnt, int E, int Etot, int N,
    int eb, const u16* __restrict__ xb, const u16* __restrict__ Wl1t,
    const u16* __restrict__ Wr1t, u16* __restrict__ xl1, u16* __restrict__ xr1,
    int Mt) {
  int b = blockIdx.x;
  if (b < eb) {
    int e = b * 256 + threadIdx.x;
    if (e >= Etot) return;
    int dst = (e < E) ? ei[E + e] : (e - E);
    atomicAdd(&hist[dst], 1);
    if (e < N) atomicAdd(&gcnt[batch[e]], 1);
    return;
  }
  b -= eb;
  gemm_body<DIN, false>(xb, Wl1t, Wr1t, F1, xl1, xr1, N, nullptr, b % Mt, b / Mt,
                        threadIdx.x);
}

// ---------------- single-pass decoupled-lookback scan (r10) ----------------
__global__ void k_scan(const int* __restrict__ hist, int* __restrict__ rowptr,
                       int* __restrict__ cursor, unsigned long long* __restrict__ pstate,
                       int* __restrict__ ctr, int n, int Etot) {
  __shared__ int tmp[256];
  __shared__ int bidS, offS;
  int t = threadIdx.x;
  if (t == 0) bidS = atomicAdd(ctr, 1);
  __syncthreads();
  int bid = bidS;
  int gid = bid * 256 + t;
  int v = (gid < n) ? hist[gid] : 0;
  tmp[t] = v;
  __syncthreads();
  for (int off = 1; off < 256; off <<= 1) {
    int add = (t >= off) ? tmp[t - off] : 0;
    __syncthreads();
    tmp[t] += add;
    __syncthreads();
  }
  if (t == 0) {
    int total = tmp[255];
    unsigned long long st =
        ((unsigned long long)(bid == 0 ? 2 : 1) << 32) | (unsigned)total;
    atomicExch(&pstate[bid], st);
    int off = 0;
    if (bid > 0) {
      int b = bid - 1;
      while (true) {
        unsigned long long s;
        do { s = atomicAdd(&pstate[b], 0ULL); } while ((s >> 32) == 0);
        off += (int)(unsigned)s;
        if ((s >> 32) == 2) break;
        b--;
      }
      atomicExch(&pstate[bid],
                 ((unsigned long long)2 << 32) | (unsigned)(off + total));
    }
    offS = off;
  }
  __syncthreads();
  int off = offS;
  if (gid < n) {
    int ex = off + tmp[t] - v;
    rowptr[gid] = ex;
    cursor[gid] = ex;
  }
  if (gid == 0) rowptr[n] = Etot;
}

__global__ void k_scatter(const int* __restrict__ ei, int* __restrict__ cursor,
                          int* __restrict__ ssrc, int E, int Etot) {
  int e = blockIdx.x * 256 + threadIdx.x;
  if (e >= Etot) return;
  int src, dst;
  if (e < E) { src = ei[e]; dst = ei[E + e]; }
  else       { src = e - E; dst = e - E; }
  int pos = atomicAdd(&cursor[dst], 1);
  ssrc[pos] = src;
}

// ---------------- quarter-wave aggregation (r6-proven) ----------------
template<int HEADS, int MODE>
__global__ __launch_bounds__(256) void k_agg(
    const u16* __restrict__ xl, const u16* __restrict__ xr,
    const u16* __restrict__ att, const u16* __restrict__ bias,
    const int* __restrict__ rowptr, const int* __restrict__ ssrc,
    void* __restrict__ outv, int n) {
  constexpr int F = HEADS * 128;
  constexpr int EPI = 4 / HEADS;
  int wave = threadIdx.x >> 6, lane = threadIdx.x & 63;
  int node = blockIdx.x * 4 + wave;
  if (node >= n) return;
  const int q = lane >> 4, l = lane & 15;
  const int eo   = (HEADS == 2) ? (q >> 1) : q;
  const int head = (HEADS == 2) ? (q & 1) : 0;
  const int ch0 = head * 128 + l * 8;

  float xrv[8], attv[8], acc[8];
  load8(xr + (size_t)node * F + ch0, xrv);
  load8(att + ch0, attv);
#pragma unroll
  for (int k = 0; k < 8; k++) acc[k] = 0.f;

  float l_run = 0.f;
  const int jb = rowptr[node], je = rowptr[node + 1];
  for (int j = jb; j < je; j += EPI) {
    int jj = j + eo;
    int src = ssrc[jj < je ? jj : (je - 1)];
    float xlv[8];
    load8(xl + (size_t)src * F + ch0, xlv);
    float s = 0.f;
#pragma unroll
    for (int k = 0; k < 8; k++) {
      float mm = xlv[k] + xrv[k];
      mm = mm > 0.f ? mm : NEG_SLOPE * mm;
      s += mm * attv[k];
    }
#pragma unroll
    for (int m = 1; m <= 8; m <<= 1) s += __shfl_xor(s, m, 64);
    float p = (jj < je) ? __expf(fminf(s, 80.f)) : 0.f;
    l_run += p;
#pragma unroll
    for (int k = 0; k < 8; k++) acc[k] += p * xlv[k];
  }

#pragma unroll
  for (int m = 16 * HEADS; m <= 32; m <<= 1) {
#pragma unroll
    for (int k = 0; k < 8; k++) acc[k] += __shfl_xor(acc[k], m, 64);
    l_run += __shfl_xor(l_run, m, 64);
  }

  if (lane < 16 * HEADS) {
    float inv = 1.f / (l_run + 1e-16f);
    if (MODE == 0) {
      short8 o;
#pragma unroll
      for (int k = 0; k < 8; k++) {
        float t = acc[k] * inv + bf2f(bias[ch0 + k]);
        t = t > 0.f ? t : (__expf(t) - 1.f);        // elu
        o[k] = (short)f2bf(t);
      }
      *(short8*)((u16*)outv + (size_t)node * F + ch0) = o;
    } else {
      float v[8];
#pragma unroll
      for (int k = 0; k < 8; k++) v[k] = acc[k] * inv + bf2f(bias[ch0 + k]);
      float* op = (float*)outv + (size_t)node * F + ch0;
      *(float4*)op = make_float4(v[0], v[1], v[2], v[3]);
      *(float4*)(op + 4) = make_float4(v[4], v[5], v[6], v[7]);
    }
  }
}

// ---------------- stats + last-block computes a,b + empty-graph sweep ----------------
// EXACTLY 256 blocks. Last block (atomic counter, no polling) derives
// a=gamma*rsqrt(var+eps), b=beta-mu*a into ab[512] fp32.
__global__ __launch_bounds__(256) void k_stats2(
    const u16* __restrict__ h, float* __restrict__ gsum, float* __restrict__ gsumsq,
    const u16* __restrict__ gamma, const u16* __restrict__ beta,
    float* __restrict__ ab, const int* __restrict__ gcnt,
    const u16* __restrict__ blin, const int* __restrict__ flag,
    void* __restrict__ out, int* __restrict__ sctr, int n, int G, float invn) {
  __shared__ float smS[8][256], smQ[8][256];
  __shared__ int lastS;
  int t = threadIdx.x;
  int rg = t >> 5, cl = t & 31;
  int ch0 = cl * 8;
  float s[8] = {}, q[8] = {};
  for (int r = blockIdx.x * 8 + rg; r < n; r += 256 * 8) {
    float v[8];
    load8(h + (size_t)r * F1 + ch0, v);
#pragma unroll
    for (int k = 0; k < 8; k++) { s[k] += v[k]; q[k] += v[k] * v[k]; }
  }
#pragma unroll
  for (int k = 0; k < 8; k++) { smS[rg][ch0 + k] = s[k]; smQ[rg][ch0 + k] = q[k]; }
  __syncthreads();
  float ts = 0.f, tq = 0.f;
#pragma unroll
  for (int g = 0; g < 8; g++) { ts += smS[g][t]; tq += smQ[g][t]; }
  atomicAdd(&gsum[t], ts);
  atomicAdd(&gsumsq[t], tq);

  __threadfence();
  __syncthreads();
  if (t == 0) lastS = (atomicAdd(sctr, 1) == 255) ? 1 : 0;
  __syncthreads();
  if (lastS) {
    __threadfence();
    float gs = atomicAdd(&gsum[t], 0.f);     // coherent read
    float gq = atomicAdd(&gsumsq[t], 0.f);
    float mu = gs * invn;
    float var = gq * invn - mu * mu;
    float a = bf2f(gamma[t]) * rsqrtf(fmaxf(var, 0.f) + 1e-5f);
    ab[t] = a;
    ab[256 + t] = bf2f(beta[t]) - mu * a;
    // empty graphs: out = blin (no agg/pool will touch them)
    for (int g = t; g < G; g += 256) {
      if (gcnt[g] == 0) {
        float o0 = bf2f(blin[0]), o1 = bf2f(blin[1]);
        if (*flag) {
          ((float*)out)[g * 2 + 0] = o0;
          ((float*)out)[g * 2 + 1] = o1;
        } else {
          ((u16*)out)[g * 2 + 0] = f2bf(o0);
          ((u16*)out)[g * 2 + 1] = f2bf(o1);
        }
      }
    }
  }
}

// ---------------- gemm2 with BN applied to A fragments (a*x+b, exact) ----------------
__global__ __launch_bounds__(256) void k_gemm2bn(
    const u16* __restrict__ A, const u16* __restrict__ Blt, const u16* __restrict__ Brt,
    u16* __restrict__ Cl, u16* __restrict__ Cr, int M, const float* __restrict__ ab) {
  const int tid = threadIdx.x;
  const int m0 = blockIdx.x * 64;
  const int n0g = blockIdx.y * 64;
  const u16* Bt; u16* C; int col0;
  if (n0g < F2) { Bt = Blt; C = Cl; col0 = n0g; }
  else          { Bt = Brt; C = Cr; col0 = n0g - F2; }

  const int wave = tid >> 6, lane = tid & 63;
  const int wm = wave >> 1, wn = wave & 1;
  const int quad = lane >> 4, l16 = lane & 15;

  floatx4 acc[2][2] = {};
#pragma unroll
  for (int k0 = 0; k0 < F1; k0 += 32) {
    float av[8], bv[8];
    *(float4*)av       = *(const float4*)(ab + k0 + quad * 8);
    *(float4*)(av + 4) = *(const float4*)(ab + k0 + quad * 8 + 4);
    *(float4*)bv       = *(const float4*)(ab + 256 + k0 + quad * 8);
    *(float4*)(bv + 4) = *(const float4*)(ab + 256 + k0 + quad * 8 + 4);
    short8 af[2], bfr[2];
#pragma unroll
    for (int mt = 0; mt < 2; mt++) {
      int row = m0 + wm * 32 + mt * 16 + l16;
      if (row > M - 1) row = M - 1;
      short8 raw = *(const short8*)(A + (size_t)row * F1 + k0 + quad * 8);
#pragma unroll
      for (int j = 0; j < 8; j++) {
        float v = av[j] * bf2f((u16)raw[j]) + bv[j];   // BN: a*helu + b
        af[mt][j] = (short)f2bf(v);
      }
    }
#pragma unroll
    for (int nt = 0; nt < 2; nt++) {
      int nn = col0 + wn * 32 + nt * 16 + l16;
      bfr[nt] = *(const short8*)(Bt + (size_t)nn * F1 + k0 + quad * 8);
    }
#pragma unroll
    for (int mt = 0; mt < 2; mt++)
#pragma unroll
      for (int nt = 0; nt < 2; nt++)
        acc[mt][nt] = __builtin_amdgcn_mfma_f32_16x16x32_bf16(af[mt], bfr[nt], acc[mt][nt], 0, 0, 0);
  }

#pragma unroll
  for (int mt = 0; mt < 2; mt++)
#pragma unroll
    for (int nt = 0; nt < 2; nt++)
#pragma unroll
      for (int r = 0; r < 4; r++) {
        int row = m0 + wm * 32 + mt * 16 + quad * 4 + r;
        if (row < M) {
          int col = col0 + wn * 32 + nt * 16 + l16;
          C[(size_t)row * F2 + col] = f2bf(acc[mt][nt][r]);
        }
      }
}

// ---------------- pool + final linear (r10) ----------------
__device__ __forceinline__ int lowerb(const int* __restrict__ a, int n, int key) {
  int lo = 0, hi = n;
  while (lo < hi) { int m = (lo + hi) >> 1; if (a[m] < key) lo = m + 1; else hi = m; }
  return lo;
}

__global__ __launch_bounds__(256) void k_poolfinal(
    const float* __restrict__ h2, const int* __restrict__ batch,
    const u16* __restrict__ Wlin, const u16* __restrict__ blin,
    void* __restrict__ out, const int* __restrict__ flag, int G, int N) {
  __shared__ float sm[4][128];
  int g = blockIdx.x;
  int wave = threadIdx.x >> 6, lane = threadIdx.x & 63;
  int jb = lowerb(batch, N, g);
  int je = lowerb(batch, N, g + 1);
  if (jb >= je) return;   // empty graph handled by k_stats2
  int ch = lane * 2;
  float c0 = 0.f, c1 = 0.f;
  for (int r = jb + wave; r < je; r += 4) {
    float2 v = *(const float2*)(h2 + (size_t)r * F2 + ch);
    c0 += v.x; c1 += v.y;
  }
  sm[wave][ch] = c0;
  sm[wave][ch + 1] = c1;
  __syncthreads();
  if (wave == 0) {
    c0 = sm[0][ch] + sm[1][ch] + sm[2][ch] + sm[3][ch];
    c1 = sm[0][ch + 1] + sm[1][ch + 1] + sm[2][ch + 1] + sm[3][ch + 1];
    float cf = fmaxf((float)(je - jb), 1.f);
    c0 /= cf; c1 /= cf;
    float s0 = c0 * bf2f(Wlin[ch * 2 + 0]) + c1 * bf2f(Wlin[(ch + 1) * 2 + 0]);
    float s1 = c0 * bf2f(Wlin[ch * 2 + 1]) + c1 * bf2f(Wlin[(ch + 1) * 2 + 1]);
#pragma unroll
    for (int m = 1; m <= 32; m <<= 1) {
      s0 += __shfl_xor(s0, m, 64);
      s1 += __shfl_xor(s1, m, 64);
    }
    if (lane == 0) {
      float o0 = s0 + bf2f(blin[0]);
      float o1 = s1 + bf2f(blin[1]);
      if (*flag) {
        ((float*)out)[g * 2 + 0] = o0;
        ((float*)out)[g * 2 + 1] = o1;
      } else {
        ((u16*)out)[g * 2 + 0] = f2bf(o0);
        ((u16*)out)[g * 2 + 1] = f2bf(o1);
      }
    }
  }
}

// ---------------- host ----------------
extern "C" void kernel_launch(void* const* d_in, const int* in_sizes, int n_in,
                              void* d_out, int out_size, void* d_ws, size_t ws_size,
                              hipStream_t stream) {
  const int* ei    = (const int*)d_in[1];
  const int* batch = (const int*)d_in[2];

  const int N = in_sizes[0] / DIN;
  const int E = in_sizes[1] / 2;
  const int G = out_size / 2;
  const int Etot = E + N;

  char* p = (char*)d_ws;
  auto alloc = [&](size_t bytes) {
    char* r = p;
    p += (bytes + 255) & ~(size_t)255;
    return r;
  };
  int*  flag     = (int*)alloc(256);
  // ---- zero region (zeroed by convert_all): hist|gsum|gsumsq|pstate|ctr|gcnt|sctr ----
  int*  hist     = (int*)alloc((size_t)N * 4);
  float* gsum    = (float*)alloc(1024);
  float* gsumsq  = (float*)alloc(1024);
  unsigned long long* pstate = (unsigned long long*)alloc(2048);
  int*  ctr      = (int*)alloc(256);
  int*  gcnt     = (int*)alloc((size_t)G * 4);
  int*  sctr     = (int*)alloc(256);
  int   zn       = (int)(((char*)sctr + 256) - (char*)hist) / 4;
  // ---- rest ----
  int*  rowptr   = (int*)alloc((size_t)(N + 1) * 4);
  int*  cursor   = (int*)alloc((size_t)N * 4);
  float* ab      = (float*)alloc(2048);
  int*  ssrc     = (int*)alloc((size_t)Etot * 4);
  u16*  xb       = (u16*)alloc((size_t)N * DIN * 2);
  u16*  pb       = (u16*)alloc(4096);
  u16*  Wl1t     = (u16*)alloc(DIN * F1 * 2);
  u16*  Wr1t     = (u16*)alloc(DIN * F1 * 2);
  u16*  Wl2t     = (u16*)alloc(F1 * F2 * 2);
  u16*  Wr2t     = (u16*)alloc(F1 * F2 * 2);
  u16*  regionA  = (u16*)alloc((size_t)N * F1 * 2);
  u16*  regionB  = (u16*)alloc((size_t)N * F1 * 2);
  u16*  regionC  = (u16*)alloc((size_t)N * F1 * 2);

  u16*  xl1  = regionA;
  u16*  xr1  = regionB;
  u16*  helu = regionC;
  u16*  xl2  = regionB;
  u16*  xr2  = regionB + (size_t)N * F2;
  float* h2  = (float*)regionA;

  // ---- D1: fused convert (+transpose, +zero, +self-detect) ----
  const int pidx[8] = {5, 6, 7, 8, 11, 12, 13, 14};
  PTab tab;
  int accum = 0;
  for (int i = 0; i < 8; i++) {
    tab.src[i] = d_in[pidx[i]];
    tab.off[i] = accum;
    accum += in_sizes[pidx[i]];
  }
  tab.off[8] = accum;
  int n4 = in_sizes[0] / 4;
  int nxb = (n4 + 255) / 256;
  int npb = (accum + 255) / 256;
  int nzb = (zn + 255) / 256;
  k_convert_all<<<nxb + npb + 512 + nzb, 256, 0, stream>>>(
      d_in[0], xb, n4, nxb, tab, pb, accum, npb,
      d_in[3], d_in[4], d_in[9], d_in[10], Wl1t, Wr1t, Wl2t, Wr2t,
      hist, zn, flag);
  u16 *pAtt1 = pb + tab.off[0], *pB1 = pb + tab.off[1], *pGamma = pb + tab.off[2],
      *pBeta = pb + tab.off[3], *pAtt2 = pb + tab.off[4], *pB2 = pb + tab.off[5],
      *pWlin = pb + tab.off[6], *pBlin = pb + tab.off[7];

  const int eb = (Etot + 255) / 256;
  const int sb = (N + 255) / 256;
  const int Mt = (N + 63) / 64;

  // ---- D2: hist(+gcnt) + gemm1 in one dispatch ----
  k_histgemm1<<<eb + Mt * 8, 256, 0, stream>>>(ei, hist, batch, gcnt, E, Etot, N,
                                               eb, xb, Wl1t, Wr1t, xl1, xr1, Mt);
  // ---- D3/D4: scan, scatter ----
  k_scan<<<sb, 256, 0, stream>>>(hist, rowptr, cursor, pstate, ctr, N, Etot);
  k_scatter<<<eb, 256, 0, stream>>>(ei, cursor, ssrc, E, Etot);

  // ---- D5: agg1 ----
  k_agg<2, 0><<<(N + 3) / 4, 256, 0, stream>>>(xl1, xr1, pAtt1, pB1, rowptr, ssrc, helu, N);

  // ---- D6: stats + a,b (last block) + empty-graph sweep ----
  k_stats2<<<256, 256, 0, stream>>>(helu, gsum, gsumsq, pGamma, pBeta, ab, gcnt,
                                    pBlin, flag, d_out, sctr, N, G, 1.0f / (float)N);

  // ---- D7: gemm2 with BN-on-A ----
  k_gemm2bn<<<dim3(Mt, 4), 256, 0, stream>>>(helu, Wl2t, Wr2t, xl2, xr2, N, ab);

  // ---- D8: agg2 ----
  k_agg<1, 1><<<(N + 3) / 4, 256, 0, stream>>>(xl2, xr2, pAtt2, pB2, rowptr, ssrc, h2, N);

  // ---- D9: pool + final ----
  k_poolfinal<<<G, 256, 0, stream>>>(h2, batch, pWlin, pBlin, d_out, flag, G, N);
}

// Round 13
// 474.665 us; speedup vs baseline: 6.1091x; 1.0717x over previous
//
#include <hip/hip_runtime.h>

// GATv2 2-layer GNN, MI355X. Inputs/out fp32 (proven r3); compute bf16.
// Round-13: un-fuse r12's histgemm1 (heterogeneous atomic+MFMA fusion ran
// 110µs vs ~45µs separate — atomic blocks poison MFMA blocks in one kernel;
// lesson logged) and drop gcnt (98-way atomic contention; empty graphs are
// handled by poolfinal's cf=max(n,1) -> blin). Keep stats2-fused a,b and
// gemm2bn (BN on A-fragments). New: #pragma unroll 2 on agg edge loop
// (VGPR 32->~48, free up to 64; overlaps gather latency).

#define DIN 128
#define F1 256
#define F2 128
#define NEG_SLOPE 0.2f

typedef unsigned short u16;
typedef __attribute__((ext_vector_type(8))) short short8;
typedef __attribute__((ext_vector_type(4))) float floatx4;

__device__ __forceinline__ float bf2f(u16 u) {
  return __uint_as_float(((unsigned int)u) << 16);
}
__device__ __forceinline__ u16 f2bf(float f) {   // round-to-nearest-even
  unsigned int x = __float_as_uint(f);
  return (u16)((x + 0x7fffu + ((x >> 16) & 1u)) >> 16);
}
__device__ __forceinline__ void load8(const u16* p, float (&f)[8]) {
  short8 v = *(const short8*)p;
#pragma unroll
  for (int k = 0; k < 8; k++) f[k] = bf2f((u16)v[k]);
}

// ---------------- fused convert + transpose + zero + self-detect (r10) ----------------
struct PTab { const void* src[8]; int off[9]; };
__global__ __launch_bounds__(256) void k_convert_all(
    const void* __restrict__ xsrc, u16* __restrict__ xb, int n4, int nxb,
    PTab t, u16* __restrict__ pb, int ptotal, int npb,
    const void* __restrict__ Wl1s, const void* __restrict__ Wr1s,
    const void* __restrict__ Wl2s, const void* __restrict__ Wr2s,
    u16* __restrict__ Wl1t, u16* __restrict__ Wr1t,
    u16* __restrict__ Wl2t, u16* __restrict__ Wr2t,
    int* __restrict__ zbase, int zn, int* __restrict__ flag) {
  __shared__ int flagS;
  int tid = threadIdx.x;
  if (tid < 64) {
    int cnt = 0;
#pragma unroll
    for (int i = 0; i < 2; ++i) {
      u16 v = ((const u16*)xsrc)[2 * (tid + 64 * i)];
      int e = (v >> 7) & 0xFF;
      if (e >= 115 && e <= 130) cnt++;
    }
#pragma unroll
    for (int m = 1; m <= 32; m <<= 1) cnt += __shfl_xor(cnt, m, 64);
    if (tid == 0) flagS = (cnt < 64) ? 1 : 0;
  }
  __syncthreads();
  const int fl = flagS;
  if (blockIdx.x == 0 && tid == 0) *flag = fl;

  int b = blockIdx.x;
  if (b < nxb) {
    int i = b * 256 + tid;
    if (i >= n4) return;
    if (fl) {
      float4 a = ((const float4*)xsrc)[i];
      ushort4 o;
      o.x = f2bf(a.x); o.y = f2bf(a.y); o.z = f2bf(a.z); o.w = f2bf(a.w);
      ((ushort4*)xb)[i] = o;
    } else {
      ((ulong1*)xb)[i] = ((const ulong1*)xsrc)[i];
    }
    return;
  }
  b -= nxb;
  if (b < npb) {
    int i = b * 256 + tid;
    if (i >= ptotal) return;
    int s = 0;
#pragma unroll
    for (int k = 1; k < 8; k++) s += (i >= t.off[k]);
    int local = i - t.off[s];
    pb[i] = fl ? f2bf(((const float*)t.src[s])[local]) : ((const u16*)t.src[s])[local];
    return;
  }
  b -= npb;
  if (b < 512) {
    int seg = b >> 7;
    int i = (b & 127) * 256 + tid;
    const void* s; u16* d; int NL, sh;
    if      (seg == 0) { s = Wl1s; d = Wl1t; NL = 256; sh = 7; }
    else if (seg == 1) { s = Wr1s; d = Wr1t; NL = 256; sh = 7; }
    else if (seg == 2) { s = Wl2s; d = Wl2t; NL = 128; sh = 8; }
    else               { s = Wr2s; d = Wr2t; NL = 128; sh = 8; }
    int n = i >> sh, k = i & ((1 << sh) - 1);
    int si = k * NL + n;
    d[i] = fl ? f2bf(((const float*)s)[si]) : ((const u16*)s)[si];
    return;
  }
  b -= 512;
  int i = b * 256 + tid;
  if (i < zn) zbase[i] = 0;
}

// ---------------- hist (standalone, no gcnt) ----------------
__global__ void k_hist(const int* __restrict__ ei, int* __restrict__ hist,
                       int E, int Etot) {
  int e = blockIdx.x * 256 + threadIdx.x;
  if (e >= Etot) return;
  int dst = (e < E) ? ei[E + e] : (e - E);
  atomicAdd(&hist[dst], 1);
}

// ---------------- single-pass decoupled-lookback scan (r10) ----------------
__global__ void k_scan(const int* __restrict__ hist, int* __restrict__ rowptr,
                       int* __restrict__ cursor, unsigned long long* __restrict__ pstate,
                       int* __restrict__ ctr, int n, int Etot) {
  __shared__ int tmp[256];
  __shared__ int bidS, offS;
  int t = threadIdx.x;
  if (t == 0) bidS = atomicAdd(ctr, 1);
  __syncthreads();
  int bid = bidS;
  int gid = bid * 256 + t;
  int v = (gid < n) ? hist[gid] : 0;
  tmp[t] = v;
  __syncthreads();
  for (int off = 1; off < 256; off <<= 1) {
    int add = (t >= off) ? tmp[t - off] : 0;
    __syncthreads();
    tmp[t] += add;
    __syncthreads();
  }
  if (t == 0) {
    int total = tmp[255];
    unsigned long long st =
        ((unsigned long long)(bid == 0 ? 2 : 1) << 32) | (unsigned)total;
    atomicExch(&pstate[bid], st);
    int off = 0;
    if (bid > 0) {
      int b = bid - 1;
      while (true) {
        unsigned long long s;
        do { s = atomicAdd(&pstate[b], 0ULL); } while ((s >> 32) == 0);
        off += (int)(unsigned)s;
        if ((s >> 32) == 2) break;
        b--;
      }
      atomicExch(&pstate[bid],
                 ((unsigned long long)2 << 32) | (unsigned)(off + total));
    }
    offS = off;
  }
  __syncthreads();
  int off = offS;
  if (gid < n) {
    int ex = off + tmp[t] - v;
    rowptr[gid] = ex;
    cursor[gid] = ex;
  }
  if (gid == 0) rowptr[n] = Etot;
}

__global__ void k_scatter(const int* __restrict__ ei, int* __restrict__ cursor,
                          int* __restrict__ ssrc, int E, int Etot) {
  int e = blockIdx.x * 256 + threadIdx.x;
  if (e >= Etot) return;
  int src, dst;
  if (e < E) { src = ei[e]; dst = ei[E + e]; }
  else       { src = e - E; dst = e - E; }
  int pos = atomicAdd(&cursor[dst], 1);
  ssrc[pos] = src;
}

// ---------------- gemm1: LDS-free, B pre-transposed (r9/r10-proven) ----------------
__global__ __launch_bounds__(256) void k_gemm1(
    const u16* __restrict__ A, const u16* __restrict__ Blt, const u16* __restrict__ Brt,
    u16* __restrict__ Cl, u16* __restrict__ Cr, int M) {
  const int tid = threadIdx.x;
  const int m0 = blockIdx.x * 64;
  const int n0g = blockIdx.y * 64;
  const u16* Bt; u16* C; int col0;
  if (n0g < F1) { Bt = Blt; C = Cl; col0 = n0g; }
  else          { Bt = Brt; C = Cr; col0 = n0g - F1; }

  const int wave = tid >> 6, lane = tid & 63;
  const int wm = wave >> 1, wn = wave & 1;
  const int quad = lane >> 4, l16 = lane & 15;

  floatx4 acc[2][2] = {};
#pragma unroll
  for (int k0 = 0; k0 < DIN; k0 += 32) {
    short8 af[2], bfr[2];
#pragma unroll
    for (int mt = 0; mt < 2; mt++) {
      int row = m0 + wm * 32 + mt * 16 + l16;
      if (row > M - 1) row = M - 1;
      af[mt] = *(const short8*)(A + (size_t)row * DIN + k0 + quad * 8);
    }
#pragma unroll
    for (int nt = 0; nt < 2; nt++) {
      int nn = col0 + wn * 32 + nt * 16 + l16;
      bfr[nt] = *(const short8*)(Bt + (size_t)nn * DIN + k0 + quad * 8);
    }
#pragma unroll
    for (int mt = 0; mt < 2; mt++)
#pragma unroll
      for (int nt = 0; nt < 2; nt++)
        acc[mt][nt] = __builtin_amdgcn_mfma_f32_16x16x32_bf16(af[mt], bfr[nt], acc[mt][nt], 0, 0, 0);
  }

#pragma unroll
  for (int mt = 0; mt < 2; mt++)
#pragma unroll
    for (int nt = 0; nt < 2; nt++)
#pragma unroll
      for (int r = 0; r < 4; r++) {
        int row = m0 + wm * 32 + mt * 16 + quad * 4 + r;
        if (row < M) {
          int col = col0 + wn * 32 + nt * 16 + l16;
          C[(size_t)row * F1 + col] = f2bf(acc[mt][nt][r]);
        }
      }
}

// ---------------- quarter-wave aggregation (r6-proven + unroll 2) ----------------
template<int HEADS, int MODE>
__global__ __launch_bounds__(256) void k_agg(
    const u16* __restrict__ xl, const u16* __restrict__ xr,
    const u16* __restrict__ att, const u16* __restrict__ bias,
    const int* __restrict__ rowptr, const int* __restrict__ ssrc,
    void* __restrict__ outv, int n) {
  constexpr int F = HEADS * 128;
  constexpr int EPI = 4 / HEADS;
  int wave = threadIdx.x >> 6, lane = threadIdx.x & 63;
  int node = blockIdx.x * 4 + wave;
  if (node >= n) return;
  const int q = lane >> 4, l = lane & 15;
  const int eo   = (HEADS == 2) ? (q >> 1) : q;
  const int head = (HEADS == 2) ? (q & 1) : 0;
  const int ch0 = head * 128 + l * 8;

  float xrv[8], attv[8], acc[8];
  load8(xr + (size_t)node * F + ch0, xrv);
  load8(att + ch0, attv);
#pragma unroll
  for (int k = 0; k < 8; k++) acc[k] = 0.f;

  float l_run = 0.f;
  const int jb = rowptr[node], je = rowptr[node + 1];
#pragma unroll 2
  for (int j = jb; j < je; j += EPI) {
    int jj = j + eo;
    int src = ssrc[jj < je ? jj : (je - 1)];
    float xlv[8];
    load8(xl + (size_t)src * F + ch0, xlv);
    float s = 0.f;
#pragma unroll
    for (int k = 0; k < 8; k++) {
      float mm = xlv[k] + xrv[k];
      mm = mm > 0.f ? mm : NEG_SLOPE * mm;
      s += mm * attv[k];
    }
#pragma unroll
    for (int m = 1; m <= 8; m <<= 1) s += __shfl_xor(s, m, 64);
    float p = (jj < je) ? __expf(fminf(s, 80.f)) : 0.f;
    l_run += p;
#pragma unroll
    for (int k = 0; k < 8; k++) acc[k] += p * xlv[k];
  }

#pragma unroll
  for (int m = 16 * HEADS; m <= 32; m <<= 1) {
#pragma unroll
    for (int k = 0; k < 8; k++) acc[k] += __shfl_xor(acc[k], m, 64);
    l_run += __shfl_xor(l_run, m, 64);
  }

  if (lane < 16 * HEADS) {
    float inv = 1.f / (l_run + 1e-16f);
    if (MODE == 0) {
      short8 o;
#pragma unroll
      for (int k = 0; k < 8; k++) {
        float t = acc[k] * inv + bf2f(bias[ch0 + k]);
        t = t > 0.f ? t : (__expf(t) - 1.f);        // elu
        o[k] = (short)f2bf(t);
      }
      *(short8*)((u16*)outv + (size_t)node * F + ch0) = o;
    } else {
      float v[8];
#pragma unroll
      for (int k = 0; k < 8; k++) v[k] = acc[k] * inv + bf2f(bias[ch0 + k]);
      float* op = (float*)outv + (size_t)node * F + ch0;
      *(float4*)op = make_float4(v[0], v[1], v[2], v[3]);
      *(float4*)(op + 4) = make_float4(v[4], v[5], v[6], v[7]);
    }
  }
}

// ---------------- stats; last block (atomic done-counter) emits a,b ----------------
// EXACTLY 256 blocks.
__global__ __launch_bounds__(256) void k_stats2(
    const u16* __restrict__ h, float* __restrict__ gsum, float* __restrict__ gsumsq,
    const u16* __restrict__ gamma, const u16* __restrict__ beta,
    float* __restrict__ ab, int* __restrict__ sctr, int n, float invn) {
  __shared__ float smS[8][256], smQ[8][256];
  __shared__ int lastS;
  int t = threadIdx.x;
  int rg = t >> 5, cl = t & 31;
  int ch0 = cl * 8;
  float s[8] = {}, q[8] = {};
  for (int r = blockIdx.x * 8 + rg; r < n; r += 256 * 8) {
    float v[8];
    load8(h + (size_t)r * F1 + ch0, v);
#pragma unroll
    for (int k = 0; k < 8; k++) { s[k] += v[k]; q[k] += v[k] * v[k]; }
  }
#pragma unroll
  for (int k = 0; k < 8; k++) { smS[rg][ch0 + k] = s[k]; smQ[rg][ch0 + k] = q[k]; }
  __syncthreads();
  float ts = 0.f, tq = 0.f;
#pragma unroll
  for (int g = 0; g < 8; g++) { ts += smS[g][t]; tq += smQ[g][t]; }
  atomicAdd(&gsum[t], ts);
  atomicAdd(&gsumsq[t], tq);

  __threadfence();
  __syncthreads();
  if (t == 0) lastS = (atomicAdd(sctr, 1) == 255) ? 1 : 0;
  __syncthreads();
  if (lastS) {
    __threadfence();
    float gs = atomicAdd(&gsum[t], 0.f);     // coherent read
    float gq = atomicAdd(&gsumsq[t], 0.f);
    float mu = gs * invn;
    float var = gq * invn - mu * mu;
    float a = bf2f(gamma[t]) * rsqrtf(fmaxf(var, 0.f) + 1e-5f);
    ab[t] = a;
    ab[256 + t] = bf2f(beta[t]) - mu * a;
  }
}

// ---------------- gemm2 with BN applied to A fragments (r12-proven) ----------------
__global__ __launch_bounds__(256) void k_gemm2bn(
    const u16* __restrict__ A, const u16* __restrict__ Blt, const u16* __restrict__ Brt,
    u16* __restrict__ Cl, u16* __restrict__ Cr, int M, const float* __restrict__ ab) {
  const int tid = threadIdx.x;
  const int m0 = blockIdx.x * 64;
  const int n0g = blockIdx.y * 64;
  const u16* Bt; u16* C; int col0;
  if (n0g < F2) { Bt = Blt; C = Cl; col0 = n0g; }
  else          { Bt = Brt; C = Cr; col0 = n0g - F2; }

  const int wave = tid >> 6, lane = tid & 63;
  const int wm = wave >> 1, wn = wave & 1;
  const int quad = lane >> 4, l16 = lane & 15;

  floatx4 acc[2][2] = {};
#pragma unroll
  for (int k0 = 0; k0 < F1; k0 += 32) {
    float av[8], bv[8];
    *(float4*)av       = *(const float4*)(ab + k0 + quad * 8);
    *(float4*)(av + 4) = *(const float4*)(ab + k0 + quad * 8 + 4);
    *(float4*)bv       = *(const float4*)(ab + 256 + k0 + quad * 8);
    *(float4*)(bv + 4) = *(const float4*)(ab + 256 + k0 + quad * 8 + 4);
    short8 af[2], bfr[2];
#pragma unroll
    for (int mt = 0; mt < 2; mt++) {
      int row = m0 + wm * 32 + mt * 16 + l16;
      if (row > M - 1) row = M - 1;
      short8 raw = *(const short8*)(A + (size_t)row * F1 + k0 + quad * 8);
#pragma unroll
      for (int j = 0; j < 8; j++) {
        float v = av[j] * bf2f((u16)raw[j]) + bv[j];   // BN: a*helu + b
        af[mt][j] = (short)f2bf(v);
      }
    }
#pragma unroll
    for (int nt = 0; nt < 2; nt++) {
      int nn = col0 + wn * 32 + nt * 16 + l16;
      bfr[nt] = *(const short8*)(Bt + (size_t)nn * F1 + k0 + quad * 8);
    }
#pragma unroll
    for (int mt = 0; mt < 2; mt++)
#pragma unroll
      for (int nt = 0; nt < 2; nt++)
        acc[mt][nt] = __builtin_amdgcn_mfma_f32_16x16x32_bf16(af[mt], bfr[nt], acc[mt][nt], 0, 0, 0);
  }

#pragma unroll
  for (int mt = 0; mt < 2; mt++)
#pragma unroll
    for (int nt = 0; nt < 2; nt++)
#pragma unroll
      for (int r = 0; r < 4; r++) {
        int row = m0 + wm * 32 + mt * 16 + quad * 4 + r;
        if (row < M) {
          int col = col0 + wn * 32 + nt * 16 + l16;
          C[(size_t)row * F2 + col] = f2bf(acc[mt][nt][r]);
        }
      }
}

// ---------------- pool + final linear (r10; empty graphs -> blin) ----------------
__device__ __forceinline__ int lowerb(const int* __restrict__ a, int n, int key) {
  int lo = 0, hi = n;
  while (lo < hi) { int m = (lo + hi) >> 1; if (a[m] < key) lo = m + 1; else hi = m; }
  return lo;
}

__global__ __launch_bounds__(256) void k_poolfinal(
    const float* __restrict__ h2, const int* __restrict__ batch,
    const u16* __restrict__ Wlin, const u16* __restrict__ blin,
    void* __restrict__ out, const int* __restrict__ flag, int G, int N) {
  __shared__ float sm[4][128];
  int g = blockIdx.x;
  int wave = threadIdx.x >> 6, lane = threadIdx.x & 63;
  int jb = lowerb(batch, N, g);
  int je = lowerb(batch, N, g + 1);
  int ch = lane * 2;
  float c0 = 0.f, c1 = 0.f;
  for (int r = jb + wave; r < je; r += 4) {
    float2 v = *(const float2*)(h2 + (size_t)r * F2 + ch);
    c0 += v.x; c1 += v.y;
  }
  sm[wave][ch] = c0;
  sm[wave][ch + 1] = c1;
  __syncthreads();
  if (wave == 0) {
    c0 = sm[0][ch] + sm[1][ch] + sm[2][ch] + sm[3][ch];
    c1 = sm[0][ch + 1] + sm[1][ch + 1] + sm[2][ch + 1] + sm[3][ch + 1];
    float cf = fmaxf((float)(je - jb), 1.f);
    c0 /= cf; c1 /= cf;
    float s0 = c0 * bf2f(Wlin[ch * 2 + 0]) + c1 * bf2f(Wlin[(ch + 1) * 2 + 0]);
    float s1 = c0 * bf2f(Wlin[ch * 2 + 1]) + c1 * bf2f(Wlin[(ch + 1) * 2 + 1]);
#pragma unroll
    for (int m = 1; m <= 32; m <<= 1) {
      s0 += __shfl_xor(s0, m, 64);
      s1 += __shfl_xor(s1, m, 64);
    }
    if (lane == 0) {
      float o0 = s0 + bf2f(blin[0]);
      float o1 = s1 + bf2f(blin[1]);
      if (*flag) {
        ((float*)out)[g * 2 + 0] = o0;
        ((float*)out)[g * 2 + 1] = o1;
      } else {
        ((u16*)out)[g * 2 + 0] = f2bf(o0);
        ((u16*)out)[g * 2 + 1] = f2bf(o1);
      }
    }
  }
}

// ---------------- host ----------------
extern "C" void kernel_launch(void* const* d_in, const int* in_sizes, int n_in,
                              void* d_out, int out_size, void* d_ws, size_t ws_size,
                              hipStream_t stream) {
  const int* ei    = (const int*)d_in[1];
  const int* batch = (const int*)d_in[2];

  const int N = in_sizes[0] / DIN;
  const int E = in_sizes[1] / 2;
  const int G = out_size / 2;
  const int Etot = E + N;

  char* p = (char*)d_ws;
  auto alloc = [&](size_t bytes) {
    char* r = p;
    p += (bytes + 255) & ~(size_t)255;
    return r;
  };
  int*  flag     = (int*)alloc(256);
  // ---- zero region (zeroed by convert_all): hist|gsum|gsumsq|pstate|ctr|sctr ----
  int*  hist     = (int*)alloc((size_t)N * 4);
  float* gsum    = (float*)alloc(1024);
  float* gsumsq  = (float*)alloc(1024);
  unsigned long long* pstate = (unsigned long long*)alloc(2048);
  int*  ctr      = (int*)alloc(256);
  int*  sctr     = (int*)alloc(256);
  int   zn       = (int)(((char*)sctr + 256) - (char*)hist) / 4;
  // ---- rest ----
  int*  rowptr   = (int*)alloc((size_t)(N + 1) * 4);
  int*  cursor   = (int*)alloc((size_t)N * 4);
  float* ab      = (float*)alloc(2048);
  int*  ssrc     = (int*)alloc((size_t)Etot * 4);
  u16*  xb       = (u16*)alloc((size_t)N * DIN * 2);
  u16*  pb       = (u16*)alloc(4096);
  u16*  Wl1t     = (u16*)alloc(DIN * F1 * 2);
  u16*  Wr1t     = (u16*)alloc(DIN * F1 * 2);
  u16*  Wl2t     = (u16*)alloc(F1 * F2 * 2);
  u16*  Wr2t     = (u16*)alloc(F1 * F2 * 2);
  u16*  regionA  = (u16*)alloc((size_t)N * F1 * 2);
  u16*  regionB  = (u16*)alloc((size_t)N * F1 * 2);
  u16*  regionC  = (u16*)alloc((size_t)N * F1 * 2);

  u16*  xl1  = regionA;
  u16*  xr1  = regionB;
  u16*  helu = regionC;
  u16*  xl2  = regionB;
  u16*  xr2  = regionB + (size_t)N * F2;
  float* h2  = (float*)regionA;

  // ---- D1: fused convert (+transpose, +zero, +self-detect) ----
  const int pidx[8] = {5, 6, 7, 8, 11, 12, 13, 14};
  PTab tab;
  int accum = 0;
  for (int i = 0; i < 8; i++) {
    tab.src[i] = d_in[pidx[i]];
    tab.off[i] = accum;
    accum += in_sizes[pidx[i]];
  }
  tab.off[8] = accum;
  int n4 = in_sizes[0] / 4;
  int nxb = (n4 + 255) / 256;
  int npb = (accum + 255) / 256;
  int nzb = (zn + 255) / 256;
  k_convert_all<<<nxb + npb + 512 + nzb, 256, 0, stream>>>(
      d_in[0], xb, n4, nxb, tab, pb, accum, npb,
      d_in[3], d_in[4], d_in[9], d_in[10], Wl1t, Wr1t, Wl2t, Wr2t,
      hist, zn, flag);
  u16 *pAtt1 = pb + tab.off[0], *pB1 = pb + tab.off[1], *pGamma = pb + tab.off[2],
      *pBeta = pb + tab.off[3], *pAtt2 = pb + tab.off[4], *pB2 = pb + tab.off[5],
      *pWlin = pb + tab.off[6], *pBlin = pb + tab.off[7];

  const int eb = (Etot + 255) / 256;
  const int sb = (N + 255) / 256;
  const int Mt = (N + 63) / 64;

  // ---- D2..D4: CSR build ----
  k_hist<<<eb, 256, 0, stream>>>(ei, hist, E, Etot);
  k_scan<<<sb, 256, 0, stream>>>(hist, rowptr, cursor, pstate, ctr, N, Etot);
  k_scatter<<<eb, 256, 0, stream>>>(ei, cursor, ssrc, E, Etot);

  // ---- D5: gemm1 ----
  k_gemm1<<<dim3(Mt, 8), 256, 0, stream>>>(xb, Wl1t, Wr1t, xl1, xr1, N);

  // ---- D6: agg1 ----
  k_agg<2, 0><<<(N + 3) / 4, 256, 0, stream>>>(xl1, xr1, pAtt1, pB1, rowptr, ssrc, helu, N);

  // ---- D7: stats + a,b (last block) ----
  k_stats2<<<256, 256, 0, stream>>>(helu, gsum, gsumsq, pGamma, pBeta, ab, sctr,
                                    N, 1.0f / (float)N);

  // ---- D8: gemm2 with BN-on-A ----
  k_gemm2bn<<<dim3(Mt, 4), 256, 0, stream>>>(helu, Wl2t, Wr2t, xl2, xr2, N, ab);

  // ---- D9: agg2 ----
  k_agg<1, 1><<<(N + 3) / 4, 256, 0, stream>>>(xl2, xr2, pAtt2, pB2, rowptr, ssrc, h2, N);

  // ---- D10: pool + final ----
  k_poolfinal<<<G, 256, 0, stream>>>(h2, batch, pWlin, pBlin, d_out, flag, G, N);
}